// Round 15
// baseline (430.425 us; speedup 1.0000x reference)
//
#include <hip/hip_runtime.h>
#include <math.h>

typedef _Float16 f16;
typedef f16 f16x8 __attribute__((ext_vector_type(8)));
typedef float f32x4 __attribute__((ext_vector_type(4)));
typedef float f32x16 __attribute__((ext_vector_type(16)));

#define EPS_F16 0.0009765625f   // jnp.finfo(float16).eps

// B=8, N=2048, C=2048, H=16, D=128, M=B*N=16384, K=C=2048

// ---------------- merged fp32 -> fp16 cast (x, W_attn, W_proj in one launch) ----
__global__ __launch_bounds__(256) void k_cast_all(const float* __restrict__ x,
                                                  const float* __restrict__ Wa,
                                                  const float* __restrict__ Wp,
                                                  f16* __restrict__ xh,
                                                  f16* __restrict__ Wah,
                                                  f16* __restrict__ Wpb) {
  long long i = (long long)blockIdx.x * blockDim.x + threadIdx.x;  // 8-elem group
  const float* src;
  f16* dst;
  long long off;
  if (i < 4194304LL) { src = x;  dst = xh;  off = i; }
  else if (i < 4718592LL) { src = Wa; dst = Wah; off = i - 4194304LL; }
  else { src = Wp; dst = Wpb; off = i - 4718592LL; }
  const float4* in4 = (const float4*)src;
  float4 a = in4[off * 2];
  float4 b = in4[off * 2 + 1];
  f16x8 o;
  o[0] = (f16)a.x; o[1] = (f16)a.y; o[2] = (f16)a.z; o[3] = (f16)a.w;
  o[4] = (f16)b.x; o[5] = (f16)b.y; o[6] = (f16)b.z; o[7] = (f16)b.w;
  *(f16x8*)(dst + off * 8) = o;
}

// ---------------- async global->LDS helper ----------------
__device__ __forceinline__ void gl2lds16(const void* g, void* l) {
  __builtin_amdgcn_global_load_lds(
      (const __attribute__((address_space(1))) void*)g,
      (__attribute__((address_space(3))) void*)l, 16, 0, 0);
}

// counted vmcnt wait + scheduling fence (NEVER drain to 0 in the main loop)
template <int VM>
__device__ __forceinline__ void wait_vm() {
  if constexpr (VM == 8)      asm volatile("s_waitcnt vmcnt(8)" ::: "memory");
  else if constexpr (VM == 4) asm volatile("s_waitcnt vmcnt(4)" ::: "memory");
  else                        asm volatile("s_waitcnt vmcnt(0)" ::: "memory");
  __builtin_amdgcn_sched_barrier(0);
}

// raw barrier with compiler memory fences on both sides
__device__ __forceinline__ void pipe_barrier() {
  __builtin_amdgcn_sched_barrier(0);
  asm volatile("" ::: "memory");
  __builtin_amdgcn_s_barrier();
  asm volatile("" ::: "memory");
  __builtin_amdgcn_sched_barrier(0);
}

// ====== 256x256 GEMM, BK=32, 4-slot LDS pipeline, 8 waves, 32x32x16 MFMA =====
// r8 pipeline (race-free over 5 validations) with the MFMA shape switched to
// v_mfma_f32_32x32x16_f16: half the MFMA instructions, higher per-inst ceiling
// (2382 vs 2075 TF ubench). LDS storage involution updated for the 32-row
// fragment read: P = L ^ (((L>>9 ^ L>>10)&1)<<5)  (bank-uniform: 8 lanes per
// 16B-class = exact minimum). Staging source and fragment-read XORs match.
// C/D mapping (HW-verified m74/m101, dtype-indep): col=lane&31,
// row=(reg&3)+8*(reg>>2)+4*(lane>>5).
// launch_bounds MUST stay (512,2): forcing 4 waves/EU spills the 128-VGPR
// accumulator (r9: 6x regression).
// MODE 0: Cout (fp32) row-major M x 2048          [final projection]
// MODE 1: Wout (fp16) (B,H,N,D) via LDS-transposed 128B-coalesced stores
//         + fused chunk partials of q^2 -> psum (q = fp16(w), scans exact in q)
template <int MODE>
__global__ __launch_bounds__(512, 2) void gemm256(const f16* __restrict__ A,
                                                  const f16* __restrict__ Bm,
                                                  float* __restrict__ Cout,
                                                  f16* __restrict__ Wout,
                                                  float* __restrict__ psum) {
  constexpr int K = 2048;
  constexpr int NT = K / 32;          // 64 K-tiles
  __shared__ alignas(16) char lds[131072];   // 4 slots x (A 16KB + B 16KB)
  const int t = threadIdx.x;
  const int lane = t & 63;
  const int wid = t >> 6;
  const int wm = wid >> 2;   // M-half owner (0..1)
  const int wn = wid & 3;    // N-quarter owner (0..3)

  // T1: XCD-aware chunked swizzle (bijective: 512 % 8 == 0)
  const int lin = blockIdx.y * 8 + blockIdx.x;     // gridDim.x == 8
  const int logical = (lin & 7) * 64 + (lin >> 3);
  const size_t bm = (size_t)(logical >> 3) * 256;
  const size_t bn = (size_t)(logical & 7) * 256;

  // staging source geometry (BK=32): thread t, chunk j in {0,1} writes LDS bytes
  // [j*8192 + t*16, +16); source element = involution image:
  // bit9 of p = t>>5, bit10 = t>>6  ->  sk ^= ((t>>5 ^ t>>6)&1)<<4 (elements)
  const int sk = ((t & 3) * 8) ^ ((((t >> 5) ^ (t >> 6)) & 1) << 4);
  size_t aOff[2], bOff[2];
#pragma unroll
  for (int j = 0; j < 2; ++j) {
    int sr = j * 128 + (t >> 6) * 16 + ((t & 63) >> 2);
    aOff[j] = (bm + (size_t)sr) * K + sk;
    bOff[j] = (bn + (size_t)sr) * K + sk;
  }
  const int t16 = t * 16;

  f32x16 acc[4][2] = {};

  auto stage_tile = [&](int kt) {
    char* base = lds + (kt & 3) * 32768;
    const size_t ko = (size_t)kt * 32;
#pragma unroll
    for (int j = 0; j < 2; ++j) {
      gl2lds16(A + aOff[j] + ko, base + j * 8192 + t16);
      gl2lds16(Bm + bOff[j] + ko, base + 16384 + j * 8192 + t16);
    }
  };

  // fragment read: row/col = lane&31 -> subtile pair idx + parity (lane>>4)&1,
  // r_in = lane&15; k = (lane>>5)*8 + kb*16 + i. XOR = ((lane>>3 ^ lane>>4)&1)<<5.
  auto compute_tile = [&](int slot) {
    const char* Ab = lds + slot * 32768 + wm * 8192;
    const char* Bb = lds + slot * 32768 + 16384 + wn * 4096;
    const int x5 = (((lane >> 3) ^ (lane >> 4)) & 1) << 5;
    const int loff = (lane & 15) * 64 + ((lane >> 5) & 1) * 16;
    const int sub = (lane >> 4) & 1;
    f16x8 bfr[2][2];
#pragma unroll
    for (int fj = 0; fj < 2; ++fj)
#pragma unroll
      for (int kb = 0; kb < 2; ++kb)
        bfr[fj][kb] = *(const f16x8*)(Bb + (fj * 2 + sub) * 1024 +
                                      ((loff + kb * 32) ^ x5));
#pragma unroll
    for (int fi = 0; fi < 4; ++fi) {
      f16x8 a0 = *(const f16x8*)(Ab + (fi * 2 + sub) * 1024 + (loff ^ x5));
      f16x8 a1 = *(const f16x8*)(Ab + (fi * 2 + sub) * 1024 + ((loff + 32) ^ x5));
      __builtin_amdgcn_s_setprio(1);
#pragma unroll
      for (int fj = 0; fj < 2; ++fj) {
        acc[fi][fj] = __builtin_amdgcn_mfma_f32_32x32x16_f16(
            a0, bfr[fj][0], acc[fi][fj], 0, 0, 0);
        acc[fi][fj] = __builtin_amdgcn_mfma_f32_32x32x16_f16(
            a1, bfr[fj][1], acc[fi][fj], 0, 0, 0);
      }
      __builtin_amdgcn_s_setprio(0);
    }
  };

  // prologue: stage tiles 0,1,2 (12 loads/thread); wait tile0 (vmcnt 8 left)
  stage_tile(0);
  stage_tile(1);
  stage_tile(2);
  wait_vm<8>();
  pipe_barrier();

  // steady state: loads for tiles kt+2, kt+3 stay in flight across the barrier
  for (int kt = 0; kt <= NT - 4; ++kt) {
    stage_tile(kt + 3);
    compute_tile(kt & 3);
    wait_vm<8>();        // tile kt+1 landed; {kt+2, kt+3} outstanding
    pipe_barrier();
  }
  // tail: NT-3, NT-2, NT-1
  compute_tile((NT - 3) & 3); wait_vm<4>(); pipe_barrier();
  compute_tile((NT - 2) & 3); wait_vm<0>(); pipe_barrier();
  compute_tile((NT - 1) & 3); pipe_barrier();

  // ---- epilogue ----  C/D: col = lane&31, row = (r&3)+8*(r>>2)+4*(lane>>5)
  const int col32 = lane & 31;
  const int rhi = 4 * (lane >> 5);
  if constexpr (MODE == 0) {
#pragma unroll
    for (int fi = 0; fi < 4; ++fi)
#pragma unroll
      for (int fj = 0; fj < 2; ++fj)
#pragma unroll
        for (int r = 0; r < 16; ++r) {
          size_t gr = bm + wm * 128 + fi * 32 + (r & 3) + 8 * (r >> 2) + rhi;
          size_t gc = bn + wn * 64 + fj * 32 + col32;
          Cout[gr * 2048 + gc] = acc[fi][fj][r];
        }
  } else {
    // (1) quantize to fp16, stash in wave-private 16KB LDS (XOR-swizzled),
    //     and accumulate chunk partials of q^2
    char* W = lds + wid * 16384;
#pragma unroll
    for (int fj = 0; fj < 2; ++fj) {
      float ss = 0.f;
#pragma unroll
      for (int fi = 0; fi < 4; ++fi)
#pragma unroll
        for (int r = 0; r < 16; ++r) {
          int row_l = fi * 32 + (r & 3) + 8 * (r >> 2) + rhi;   // 0..127
          int d_l = fj * 32 + col32;                            // 0..63
          f16 q = (f16)acc[fi][fj][r];
          *(f16*)(W + row_l * 128 +
                  ((d_l * 2) ^ (((row_l >> 2) & 3) << 5))) = q;
          float qf = (float)q;
          ss += qf * qf;
        }
      ss += __shfl_xor(ss, 32);   // lane & lane^32 hold complementary row-halves
      if (lane < 32) {
        int b = (int)(bm >> 11);
        int h = (int)(bn >> 7) + (wn >> 1);
        int chunk = (int)((bm & 2047) >> 7) + wm;
        int d = (wn & 1) * 64 + fj * 32 + lane;
        psum[(((size_t)(b * 16 + h)) * 16 + chunk) * 128 + d] = ss;
      }
    }
    asm volatile("s_waitcnt lgkmcnt(0)" ::: "memory");
    __builtin_amdgcn_sched_barrier(0);
    // (2) read back f16x8 per lane -> 128B-coalesced stores. Address XOR
    // compensates the stored involution (verified r8; storage formula
    // unchanged, only the producer loop changed).
#pragma unroll
    for (int it = 0; it < 16; ++it) {
      int row_l = it * 8 + (lane >> 3);
      int g2 = (row_l >> 2) & 3;
      int c_p = lane & 7;
      f16x8 v = *(const f16x8*)(W + row_l * 128 + ((c_p * 16) ^ (g2 << 5)));
      size_t gr = bm + wm * 128 + row_l;
      int h = (int)(bn >> 7) + (wn >> 1);
      int d = (wn & 1) * 64 + c_p * 8;
      *(f16x8*)(Wout + (((gr >> 11) * 16 + h) * 2048 + (gr & 2047)) * 128 + d) =
          v;
    }
  }
}

// ====== k_tmp, strip-mined: 4 strips of 32 rows, LDS 32x129 (16.5KB) ======
__global__ __launch_bounds__(128) void k_tmp(const f16* __restrict__ w,
                                             const float* __restrict__ psum,
                                             const float* __restrict__ dbias,
                                             const float* __restrict__ temp,
                                             float* __restrict__ tmp) {
  __shared__ float ratio[32 * 129];
  __shared__ float part[2][32];
  int blk = blockIdx.x;
  int bh = blk >> 4, chunk = blk & 15;
  int h = bh & 15;
  int d = threadIdx.x;
  float cum = 0.f;
  for (int c = 0; c < chunk; ++c)
    cum += psum[((size_t)bh * 16 + c) * 128 + d];
  const f16* base =
      w + ((size_t)bh * 2048 + (size_t)chunk * 128) * 128 + d;
  const float tb = temp[h];
  const int r = d & 31;        // row owned in sum phase
  const int q = d >> 5;        // quarter of d-range
#pragma unroll
  for (int s = 0; s < 4; ++s) {
    for (int i = 0; i < 32; ++i) {
      float v = (float)base[(size_t)(s * 32 + i) * 128];
      float sq = v * v;
      cum += sq;
      ratio[i * 129 + d] = sq / fmaxf(cum, EPS_F16);
    }
    __syncthreads();
    float p = 0.f;
#pragma unroll
    for (int j = 0; j < 32; ++j) p += ratio[r * 129 + q * 32 + j];
    p += __shfl_xor(p, 32);
    if ((d & 32) == 0) part[d >> 6][r] = p;
    __syncthreads();
    if (d < 32) {
      float tot = part[0][d] + part[1][d];
      int n = chunk * 128 + s * 32 + d;
      tmp[(size_t)bh * 2048 + n] = (tot + 128.f * dbias[h * 2048 + n]) * tb;
    }
    __syncthreads();
  }
}

// pass C partials with fused softmax: psum2[bh][c][d] = sum_i q^2*Pi,
// pisum[bh][c] = sum_i Pi. Pi recomputed locally from tmp.
__global__ __launch_bounds__(128) void k_partial2(const f16* __restrict__ w,
                                                  const float* __restrict__ tmp,
                                                  float* __restrict__ psum2,
                                                  float* __restrict__ pisum) {
  __shared__ float Pi_loc[128];
  int blk = blockIdx.x;
  int bh = blk >> 4, chunk = blk & 15;
  int b = bh >> 4, h = bh & 15;
  int d = threadIdx.x;
  {
    int tid = threadIdx.x;
    int n = chunk * 128 + tid;
    float v[16];
    float mx = -1e30f;
#pragma unroll
    for (int hh = 0; hh < 16; ++hh) {
      v[hh] = tmp[((size_t)(b * 16 + hh)) * 2048 + n];
      mx = fmaxf(mx, v[hh]);
    }
    float s = 0.f;
#pragma unroll
    for (int hh = 0; hh < 16; ++hh) {
      v[hh] = expf(v[hh] - mx);
      s += v[hh];
    }
    Pi_loc[tid] = v[h] * (1.f / s);
  }
  __syncthreads();
  const f16* base =
      w + ((size_t)bh * 2048 + (size_t)chunk * 128) * 128 + d;
  float s = 0.f, sp = 0.f;
#pragma unroll 4
  for (int i = 0; i < 128; ++i) {
    float p = Pi_loc[i];
    float v = (float)base[(size_t)i * 128];
    s += v * v * p;
    sp += p;
  }
  psum2[(size_t)blk * 128 + d] = s;
  if (d == 0) pisum[blk] = sp;
}

// pass C replay with fused softmax + inline prefixes:
// dots = cum(q^2*Pi)/(cum(Pi)+eps); y = -(q*Pi)/(1+dots), fp16, (B,N,C)
__global__ __launch_bounds__(128) void k_y(const f16* __restrict__ w,
                                           const float* __restrict__ tmp,
                                           const float* __restrict__ psum2,
                                           const float* __restrict__ pisum,
                                           f16* __restrict__ yout) {
  __shared__ float Pi_loc[128];
  int blk = blockIdx.x;
  int bh = blk >> 4, chunk = blk & 15;
  int b = bh >> 4, h = bh & 15;
  int d = threadIdx.x;
  {
    int tid = threadIdx.x;
    int n = chunk * 128 + tid;
    float v[16];
    float mx = -1e30f;
#pragma unroll
    for (int hh = 0; hh < 16; ++hh) {
      v[hh] = tmp[((size_t)(b * 16 + hh)) * 2048 + n];
      mx = fmaxf(mx, v[hh]);
    }
    float s = 0.f;
#pragma unroll
    for (int hh = 0; hh < 16; ++hh) {
      v[hh] = expf(v[hh] - mx);
      s += v[hh];
    }
    Pi_loc[tid] = v[h] * (1.f / s);
  }
  __syncthreads();
  float cum = 0.f, cpi = 0.f;
  for (int c = 0; c < chunk; ++c) {
    cum += psum2[((size_t)bh * 16 + c) * 128 + d];
    cpi += pisum[bh * 16 + c];
  }
  const f16* base =
      w + ((size_t)bh * 2048 + (size_t)chunk * 128) * 128 + d;
  for (int i = 0; i < 128; ++i) {
    float p = Pi_loc[i];
    float v = (float)base[(size_t)i * 128];
    cum += v * v * p;
    cpi += p;
    float dots = cum / (cpi + EPS_F16);
    float attn = 1.f / (1.f + dots);
    float y = -(v * p) * attn;
    int n = chunk * 128 + i;
    yout[((size_t)(b * 2048 + n)) * 2048 + h * 128 + d] = (f16)y;
  }
}

// ---------------- launcher ----------------
extern "C" void kernel_launch(void* const* d_in, const int* in_sizes, int n_in,
                              void* d_out, int out_size, void* d_ws, size_t ws_size,
                              hipStream_t stream) {
  const float* x     = (const float*)d_in[0];
  const float* Wa    = (const float*)d_in[1];
  const float* Wp    = (const float*)d_in[2];
  const float* temp  = (const float*)d_in[3];
  const float* dbias = (const float*)d_in[4];
  float* out = (float*)d_out;

  char* ws = (char*)d_ws;
  // workspace layout (bytes)
  constexpr size_t OFF_W   = 0;                        // w fp16 (B,H,N,D): 67108864
  constexpr size_t OFF_XH  = 67108864;                 // x fp16 (reused as y fp16): 67108864
  constexpr size_t OFF_WAH = OFF_XH + 67108864;        // W_attn fp16: 8388608
  constexpr size_t OFF_WPB = OFF_WAH + 8388608;        // W_proj fp16: 8388608
  constexpr size_t OFF_TMP = OFF_WPB + 8388608;        // tmp (B,H,N) fp32
  constexpr size_t OFF_PS  = OFF_TMP + 2097152;        // chunk partials
  constexpr size_t OFF_PIS = OFF_PS + 1048576;         // Pi chunk partials

  f16*   w    = (f16*)(ws + OFF_W);
  f16*   xh   = (f16*)(ws + OFF_XH);   // later reused as y (fp16)
  f16*   Wah  = (f16*)(ws + OFF_WAH);
  f16*   Wpb  = (f16*)(ws + OFF_WPB);
  float* tmp  = (float*)(ws + OFF_TMP);
  float* psum = (float*)(ws + OFF_PS);
  float* pis  = (float*)(ws + OFF_PIS);

  // merged casts (x, W_attn, W_proj): 5242880 8-elem groups
  k_cast_all<<<20480, 256, 0, stream>>>(x, Wa, Wp, xh, Wah, Wpb);

  // GEMM1 (fp16, 256^2, 4-slot counted-vmcnt, 32x32x16): w = fp16(x @ W_attn^T)
  gemm256<1><<<dim3(8, 64), 512, 0, stream>>>(xh, Wah, nullptr, w, psum);

  // scan A replay (strip-mined LDS, prefix inline)
  k_tmp<<<2048, 128, 0, stream>>>(w, psum, dbias, temp, tmp);

  // scan C: partials (softmax fused), then replay (softmax + prefixes inline)
  k_partial2<<<2048, 128, 0, stream>>>(w, tmp, psum, pis);
  k_y<<<2048, 128, 0, stream>>>(w, tmp, psum, pis, xh);

  // GEMM2 (fp16, 256^2, 4-slot counted-vmcnt, 32x32x16): out = y @ W_proj^T
  gemm256<0><<<dim3(8, 64), 512, 0, stream>>>(xh, Wpb, out, nullptr, nullptr);
}

// Round 16
// 399.056 us; speedup vs baseline: 1.0786x; 1.0786x over previous
//
#include <hip/hip_runtime.h>
#include <math.h>

typedef _Float16 f16;
typedef f16 f16x8 __attribute__((ext_vector_type(8)));
typedef float f32x4 __attribute__((ext_vector_type(4)));

#define EPS_F16 0.0009765625f   // jnp.finfo(float16).eps

// B=8, N=2048, C=2048, H=16, D=128, M=B*N=16384, K=C=2048

// ---------------- merged fp32 -> fp16 cast (x, W_attn, W_proj in one launch) ----
__global__ __launch_bounds__(256) void k_cast_all(const float* __restrict__ x,
                                                  const float* __restrict__ Wa,
                                                  const float* __restrict__ Wp,
                                                  f16* __restrict__ xh,
                                                  f16* __restrict__ Wah,
                                                  f16* __restrict__ Wpb) {
  long long i = (long long)blockIdx.x * blockDim.x + threadIdx.x;  // 8-elem group
  const float* src;
  f16* dst;
  long long off;
  if (i < 4194304LL) { src = x;  dst = xh;  off = i; }
  else if (i < 4718592LL) { src = Wa; dst = Wah; off = i - 4194304LL; }
  else { src = Wp; dst = Wpb; off = i - 4718592LL; }
  const float4* in4 = (const float4*)src;
  float4 a = in4[off * 2];
  float4 b = in4[off * 2 + 1];
  f16x8 o;
  o[0] = (f16)a.x; o[1] = (f16)a.y; o[2] = (f16)a.z; o[3] = (f16)a.w;
  o[4] = (f16)b.x; o[5] = (f16)b.y; o[6] = (f16)b.z; o[7] = (f16)b.w;
  *(f16x8*)(dst + off * 8) = o;
}

// ---------------- async global->LDS helper ----------------
__device__ __forceinline__ void gl2lds16(const void* g, void* l) {
  __builtin_amdgcn_global_load_lds(
      (const __attribute__((address_space(1))) void*)g,
      (__attribute__((address_space(3))) void*)l, 16, 0, 0);
}

// counted vmcnt wait + scheduling fence (NEVER drain to 0 in the main loop)
template <int VM>
__device__ __forceinline__ void wait_vm() {
  if constexpr (VM == 8)      asm volatile("s_waitcnt vmcnt(8)" ::: "memory");
  else if constexpr (VM == 4) asm volatile("s_waitcnt vmcnt(4)" ::: "memory");
  else                        asm volatile("s_waitcnt vmcnt(0)" ::: "memory");
  __builtin_amdgcn_sched_barrier(0);
}

// raw barrier with compiler memory fences on both sides
__device__ __forceinline__ void pipe_barrier() {
  __builtin_amdgcn_sched_barrier(0);
  asm volatile("" ::: "memory");
  __builtin_amdgcn_s_barrier();
  asm volatile("" ::: "memory");
  __builtin_amdgcn_sched_barrier(0);
}

// ====== 256x256 GEMM, BK=32, 4-slot LDS pipeline (prefetch dist 3), 8 waves ====
// EXACT round-8/14 form (best measured: ~146 us each, race-free over 5
// validations, 0 bank conflicts). 16x16x32 MFMA — the 32x32x16 port (r15) was
// correct but 8% slower (1.26e7 bank conflicts from the changed read phasing).
// st_16x32 XOR swizzle. Counted vmcnt(8) keeps 2 tiles of loads in flight
// across every barrier. launch_bounds MUST stay (512,2): forcing 4 waves/EU
// spills the 128-VGPR accumulator (r9: 6x regression).
// MODE 0: Cout (fp32) row-major M x 2048          [final projection]
// MODE 1: Wout (fp16) (B,H,N,D) via LDS-transposed 128B-coalesced stores
//         + fused chunk partials of q^2 -> psum (q = fp16(w), scans exact in q)
template <int MODE>
__global__ __launch_bounds__(512, 2) void gemm256(const f16* __restrict__ A,
                                                  const f16* __restrict__ Bm,
                                                  float* __restrict__ Cout,
                                                  f16* __restrict__ Wout,
                                                  float* __restrict__ psum) {
  constexpr int K = 2048;
  constexpr int NT = K / 32;          // 64 K-tiles
  __shared__ alignas(16) char lds[131072];   // 4 slots x (A 16KB + B 16KB)
  const int t = threadIdx.x;
  const int lane = t & 63;
  const int wid = t >> 6;
  const int wm = wid >> 2;   // M-half owner (0..1)
  const int wn = wid & 3;    // N-quarter owner (0..3)

  // T1: XCD-aware chunked swizzle (bijective: 512 % 8 == 0)
  const int lin = blockIdx.y * 8 + blockIdx.x;     // gridDim.x == 8
  const int logical = (lin & 7) * 64 + (lin >> 3);
  const size_t bm = (size_t)(logical >> 3) * 256;
  const size_t bn = (size_t)(logical & 7) * 256;

  // staging source geometry (BK=32): thread t, chunk j in {0,1} writes LDS bytes
  // [j*8192 + t*16, +16) of the 16KB matrix region; source = involution image.
  const int sk = ((t & 3) * 8) ^ (((t >> 5) & 1) << 4);
  size_t aOff[2], bOff[2];
#pragma unroll
  for (int j = 0; j < 2; ++j) {
    int sr = j * 128 + (t >> 6) * 16 + ((t & 63) >> 2);
    aOff[j] = (bm + (size_t)sr) * K + sk;
    bOff[j] = (bn + (size_t)sr) * K + sk;
  }
  const int t16 = t * 16;

  // per-lane fragment byte offset within a 1024B subtile (same XOR involution)
  const int lbyte = (((lane & 15) * 64 + (lane >> 4) * 16) ^ ((lane & 8) << 2));

  f32x4 acc[8][4] = {};

  auto stage_tile = [&](int kt) {
    char* base = lds + (kt & 3) * 32768;
    const size_t ko = (size_t)kt * 32;
#pragma unroll
    for (int j = 0; j < 2; ++j) {
      gl2lds16(A + aOff[j] + ko, base + j * 8192 + t16);
      gl2lds16(Bm + bOff[j] + ko, base + 16384 + j * 8192 + t16);
    }
  };

  auto compute_tile = [&](int slot) {
    const char* Ab = lds + slot * 32768 + wm * 8192 + lbyte;
    const char* Bb = lds + slot * 32768 + 16384 + wn * 4096 + lbyte;
    f16x8 bfr[4];
#pragma unroll
    for (int fj = 0; fj < 4; ++fj) bfr[fj] = *(const f16x8*)(Bb + fj * 1024);
#pragma unroll
    for (int q = 0; q < 4; ++q) {
      f16x8 af0 = *(const f16x8*)(Ab + (q * 2) * 1024);
      f16x8 af1 = *(const f16x8*)(Ab + (q * 2 + 1) * 1024);
      __builtin_amdgcn_s_setprio(1);
#pragma unroll
      for (int fj = 0; fj < 4; ++fj) {
        acc[q * 2][fj] = __builtin_amdgcn_mfma_f32_16x16x32_f16(
            af0, bfr[fj], acc[q * 2][fj], 0, 0, 0);
        acc[q * 2 + 1][fj] = __builtin_amdgcn_mfma_f32_16x16x32_f16(
            af1, bfr[fj], acc[q * 2 + 1][fj], 0, 0, 0);
      }
      __builtin_amdgcn_s_setprio(0);
    }
  };

  // prologue: stage tiles 0,1,2 (12 loads/thread); wait tile0 (vmcnt 8 left)
  stage_tile(0);
  stage_tile(1);
  stage_tile(2);
  wait_vm<8>();
  pipe_barrier();

  // steady state: loads for tiles kt+2, kt+3 stay in flight across the barrier
  for (int kt = 0; kt <= NT - 4; ++kt) {
    stage_tile(kt + 3);
    compute_tile(kt & 3);
    wait_vm<8>();        // tile kt+1 landed; {kt+2, kt+3} outstanding
    pipe_barrier();
  }
  // tail: NT-3, NT-2, NT-1
  compute_tile((NT - 3) & 3); wait_vm<4>(); pipe_barrier();
  compute_tile((NT - 2) & 3); wait_vm<0>(); pipe_barrier();
  compute_tile((NT - 1) & 3); pipe_barrier();

  // ---- epilogue ----
  const int col = lane & 15;
  const int rb = (lane >> 4) * 4;
  if constexpr (MODE == 0) {
#pragma unroll
    for (int fi = 0; fi < 8; ++fi)
#pragma unroll
      for (int fj = 0; fj < 4; ++fj)
#pragma unroll
        for (int r = 0; r < 4; ++r) {
          size_t gr = bm + wm * 128 + fi * 16 + rb + r;   // row in (B*N)
          size_t gc = bn + wn * 64 + fj * 16 + col;       // out channel
          Cout[gr * 2048 + gc] = acc[fi][fj][r];
        }
  } else {
    // (1) quantize to fp16, stash in wave-private 16KB LDS (XOR-swizzled),
    //     and accumulate chunk partials of q^2
    char* W = lds + wid * 16384;
#pragma unroll
    for (int fj = 0; fj < 4; ++fj) {
      float ss = 0.f;
#pragma unroll
      for (int fi = 0; fi < 8; ++fi)
#pragma unroll
        for (int r = 0; r < 4; ++r) {
          int row_l = fi * 16 + rb + r;           // 0..127
          int d_l = fj * 16 + col;                // 0..63
          f16 q = (f16)acc[fi][fj][r];
          *(f16*)(W + row_l * 128 +
                  ((d_l * 2) ^ (((row_l >> 2) & 3) << 5))) = q;
          float qf = (float)q;
          ss += qf * qf;
        }
      ss += __shfl_xor(ss, 16);
      ss += __shfl_xor(ss, 32);
      if (lane < 16) {
        int b = (int)(bm >> 11);
        int h = (int)(bn >> 7) + (wn >> 1);
        int chunk = (int)((bm & 2047) >> 7) + wm;
        int d = (wn & 1) * 64 + fj * 16 + lane;
        psum[(((size_t)(b * 16 + h)) * 16 + chunk) * 128 + d] = ss;
      }
    }
    asm volatile("s_waitcnt lgkmcnt(0)" ::: "memory");
    __builtin_amdgcn_sched_barrier(0);
    // (2) read back f16x8 per lane -> 128B-coalesced stores. Address XOR
    // compensates the stored involution (verified r8).
#pragma unroll
    for (int it = 0; it < 16; ++it) {
      int row_l = it * 8 + (lane >> 3);
      int g2 = (row_l >> 2) & 3;
      int c_p = lane & 7;
      f16x8 v = *(const f16x8*)(W + row_l * 128 + ((c_p * 16) ^ (g2 << 5)));
      size_t gr = bm + wm * 128 + row_l;
      int h = (int)(bn >> 7) + (wn >> 1);
      int d = (wn & 1) * 64 + c_p * 8;
      *(f16x8*)(Wout + (((gr >> 11) * 16 + h) * 2048 + (gr & 2047)) * 128 + d) =
          v;
    }
  }
}

// ====== k_tmp, strip-mined: 4 strips of 32 rows, LDS 32x129 (16.5KB) ======
// Was 64KB ratio tile (2 blocks/CU, 4 waves/CU). Now ~8 blocks/CU. (r14: -50us)
__global__ __launch_bounds__(128) void k_tmp(const f16* __restrict__ w,
                                             const float* __restrict__ psum,
                                             const float* __restrict__ dbias,
                                             const float* __restrict__ temp,
                                             float* __restrict__ tmp) {
  __shared__ float ratio[32 * 129];
  __shared__ float part[2][32];
  int blk = blockIdx.x;
  int bh = blk >> 4, chunk = blk & 15;
  int h = bh & 15;
  int d = threadIdx.x;
  float cum = 0.f;
  for (int c = 0; c < chunk; ++c)
    cum += psum[((size_t)bh * 16 + c) * 128 + d];
  const f16* base =
      w + ((size_t)bh * 2048 + (size_t)chunk * 128) * 128 + d;
  const float tb = temp[h];
  const int r = d & 31;        // row owned in sum phase
  const int q = d >> 5;        // quarter of d-range
#pragma unroll
  for (int s = 0; s < 4; ++s) {
    for (int i = 0; i < 32; ++i) {
      float v = (float)base[(size_t)(s * 32 + i) * 128];
      float sq = v * v;
      cum += sq;
      ratio[i * 129 + d] = sq / fmaxf(cum, EPS_F16);
    }
    __syncthreads();
    float p = 0.f;
#pragma unroll
    for (int j = 0; j < 32; ++j) p += ratio[r * 129 + q * 32 + j];
    p += __shfl_xor(p, 32);
    if ((d & 32) == 0) part[d >> 6][r] = p;
    __syncthreads();
    if (d < 32) {
      float tot = part[0][d] + part[1][d];
      int n = chunk * 128 + s * 32 + d;
      tmp[(size_t)bh * 2048 + n] = (tot + 128.f * dbias[h * 2048 + n]) * tb;
    }
    __syncthreads();
  }
}

// pass C partials with fused softmax: psum2[bh][c][d] = sum_i q^2*Pi,
// pisum[bh][c] = sum_i Pi. Pi recomputed locally from tmp.
__global__ __launch_bounds__(128) void k_partial2(const f16* __restrict__ w,
                                                  const float* __restrict__ tmp,
                                                  float* __restrict__ psum2,
                                                  float* __restrict__ pisum) {
  __shared__ float Pi_loc[128];
  int blk = blockIdx.x;
  int bh = blk >> 4, chunk = blk & 15;
  int b = bh >> 4, h = bh & 15;
  int d = threadIdx.x;
  {
    int tid = threadIdx.x;
    int n = chunk * 128 + tid;
    float v[16];
    float mx = -1e30f;
#pragma unroll
    for (int hh = 0; hh < 16; ++hh) {
      v[hh] = tmp[((size_t)(b * 16 + hh)) * 2048 + n];
      mx = fmaxf(mx, v[hh]);
    }
    float s = 0.f;
#pragma unroll
    for (int hh = 0; hh < 16; ++hh) {
      v[hh] = expf(v[hh] - mx);
      s += v[hh];
    }
    Pi_loc[tid] = v[h] * (1.f / s);
  }
  __syncthreads();
  const f16* base =
      w + ((size_t)bh * 2048 + (size_t)chunk * 128) * 128 + d;
  float s = 0.f, sp = 0.f;
#pragma unroll 4
  for (int i = 0; i < 128; ++i) {
    float p = Pi_loc[i];
    float v = (float)base[(size_t)i * 128];
    s += v * v * p;
    sp += p;
  }
  psum2[(size_t)blk * 128 + d] = s;
  if (d == 0) pisum[blk] = sp;
}

// pass C replay with fused softmax + inline prefixes:
// dots = cum(q^2*Pi)/(cum(Pi)+eps); y = -(q*Pi)/(1+dots), fp16, (B,N,C)
__global__ __launch_bounds__(128) void k_y(const f16* __restrict__ w,
                                           const float* __restrict__ tmp,
                                           const float* __restrict__ psum2,
                                           const float* __restrict__ pisum,
                                           f16* __restrict__ yout) {
  __shared__ float Pi_loc[128];
  int blk = blockIdx.x;
  int bh = blk >> 4, chunk = blk & 15;
  int b = bh >> 4, h = bh & 15;
  int d = threadIdx.x;
  {
    int tid = threadIdx.x;
    int n = chunk * 128 + tid;
    float v[16];
    float mx = -1e30f;
#pragma unroll
    for (int hh = 0; hh < 16; ++hh) {
      v[hh] = tmp[((size_t)(b * 16 + hh)) * 2048 + n];
      mx = fmaxf(mx, v[hh]);
    }
    float s = 0.f;
#pragma unroll
    for (int hh = 0; hh < 16; ++hh) {
      v[hh] = expf(v[hh] - mx);
      s += v[hh];
    }
    Pi_loc[tid] = v[h] * (1.f / s);
  }
  __syncthreads();
  float cum = 0.f, cpi = 0.f;
  for (int c = 0; c < chunk; ++c) {
    cum += psum2[((size_t)bh * 16 + c) * 128 + d];
    cpi += pisum[bh * 16 + c];
  }
  const f16* base =
      w + ((size_t)bh * 2048 + (size_t)chunk * 128) * 128 + d;
  for (int i = 0; i < 128; ++i) {
    float p = Pi_loc[i];
    float v = (float)base[(size_t)i * 128];
    cum += v * v * p;
    cpi += p;
    float dots = cum / (cpi + EPS_F16);
    float attn = 1.f / (1.f + dots);
    float y = -(v * p) * attn;
    int n = chunk * 128 + i;
    yout[((size_t)(b * 2048 + n)) * 2048 + h * 128 + d] = (f16)y;
  }
}

// ---------------- launcher ----------------
extern "C" void kernel_launch(void* const* d_in, const int* in_sizes, int n_in,
                              void* d_out, int out_size, void* d_ws, size_t ws_size,
                              hipStream_t stream) {
  const float* x     = (const float*)d_in[0];
  const float* Wa    = (const float*)d_in[1];
  const float* Wp    = (const float*)d_in[2];
  const float* temp  = (const float*)d_in[3];
  const float* dbias = (const float*)d_in[4];
  float* out = (float*)d_out;

  char* ws = (char*)d_ws;
  // workspace layout (bytes)
  constexpr size_t OFF_W   = 0;                        // w fp16 (B,H,N,D): 67108864
  constexpr size_t OFF_XH  = 67108864;                 // x fp16 (reused as y fp16): 67108864
  constexpr size_t OFF_WAH = OFF_XH + 67108864;        // W_attn fp16: 8388608
  constexpr size_t OFF_WPB = OFF_WAH + 8388608;        // W_proj fp16: 8388608
  constexpr size_t OFF_TMP = OFF_WPB + 8388608;        // tmp (B,H,N) fp32
  constexpr size_t OFF_PS  = OFF_TMP + 2097152;        // chunk partials
  constexpr size_t OFF_PIS = OFF_PS + 1048576;         // Pi chunk partials

  f16*   w    = (f16*)(ws + OFF_W);
  f16*   xh   = (f16*)(ws + OFF_XH);   // later reused as y (fp16)
  f16*   Wah  = (f16*)(ws + OFF_WAH);
  f16*   Wpb  = (f16*)(ws + OFF_WPB);
  float* tmp  = (float*)(ws + OFF_TMP);
  float* psum = (float*)(ws + OFF_PS);
  float* pis  = (float*)(ws + OFF_PIS);

  // merged casts (x, W_attn, W_proj): 5242880 8-elem groups
  k_cast_all<<<20480, 256, 0, stream>>>(x, Wa, Wp, xh, Wah, Wpb);

  // GEMM1 (fp16, 256^2, 4-slot counted-vmcnt): w = fp16(x @ W_attn^T)
  gemm256<1><<<dim3(8, 64), 512, 0, stream>>>(xh, Wah, nullptr, w, psum);

  // scan A replay (strip-mined LDS, prefix inline)
  k_tmp<<<2048, 128, 0, stream>>>(w, psum, dbias, temp, tmp);

  // scan C: partials (softmax fused), then replay (softmax + prefixes inline)
  k_partial2<<<2048, 128, 0, stream>>>(w, tmp, psum, pis);
  k_y<<<2048, 128, 0, stream>>>(w, tmp, psum, pis, xh);

  // GEMM2 (fp16, 256^2, 4-slot counted-vmcnt): out = y @ W_proj^T
  gemm256<0><<<dim3(8, 64), 512, 0, stream>>>(xh, Wpb, out, nullptr, nullptr);
}